// Round 1
// baseline (1476.640 us; speedup 1.0000x reference)
//
#include <hip/hip_runtime.h>

// ProposalLayer: prop = relu(F^T W1 + b1) W2 + b2 ; top-512 by prop[...,7] ; gather rows.
// Inputs: points[8,65536,3] (UNUSED), features[8,256,65536], W1[256,256], b1[256],
//         W2[256,8], b2[8], topk(=512 scalar).
// Output: [8,512,8] f32, rows sorted by score desc (ties: lower index first).

#define NB 8
#define NC 256
#define NPTS 65536
#define NHID 256
#define NOUT 8
#define KTOP 512

#define TN 64   // points per block
#define KC 32   // c-chunk staged in LDS

// ---------------------------------------------------------------------------
// Kernel 1: fused FC1(relu)+FC2. grid=(NPTS/TN, NB), block=256 (4 waves).
// Tile: all 256 hid x 64 pts. Per-thread 8 hid x 8 pts register tile.
// Thread map: w=tid>>6 (wave), l=tid&63, g_h=l>>3, g_p=l&7
//   hid = w*64 + g_h*8 + j   (8 contiguous; 8-lane broadcast on LDS read)
//   pt  = g_p*8 + p          (8 contiguous; 8-lane broadcast on LDS read)
// ---------------------------------------------------------------------------
__global__ __launch_bounds__(256)
void fused_mlp_kernel(const float* __restrict__ feat,
                      const float* __restrict__ W1,
                      const float* __restrict__ b1,
                      const float* __restrict__ W2,
                      const float* __restrict__ b2,
                      float* __restrict__ prop,
                      float* __restrict__ score)
{
    __shared__ __align__(16) float W1s[KC][NHID]; // 32 KB
    __shared__ __align__(16) float Fs[KC][TN];    // 8 KB

    const int b      = blockIdx.y;
    const int ptbase = blockIdx.x * TN;
    const int tid    = threadIdx.x;
    const int w      = tid >> 6;
    const int l      = tid & 63;
    const int g_h    = l >> 3;
    const int g_p    = l & 7;
    const int hid0   = w * 64 + g_h * 8;
    const int pt0    = g_p * 8;

    float acc[8][8];
    #pragma unroll
    for (int j = 0; j < 8; ++j)
        #pragma unroll
        for (int p = 0; p < 8; ++p) acc[j][p] = 0.f;

    const float* fb = feat + (size_t)b * NC * NPTS + ptbase;

    for (int c0 = 0; c0 < NC; c0 += KC) {
        __syncthreads();
        // stage W1 chunk [KC][256] : 2048 float4, 8 per thread (linear, coalesced)
        #pragma unroll
        for (int k = 0; k < 8; ++k) {
            int q   = tid + k * 256;
            int row = q >> 6;
            int col = (q & 63) * 4;
            *(float4*)&W1s[row][col] =
                *(const float4*)(W1 + (size_t)(c0 + row) * NHID + col);
        }
        // stage F chunk [KC][64] : 512 float4, 2 per thread
        #pragma unroll
        for (int k = 0; k < 2; ++k) {
            int q   = tid + k * 256;
            int row = q >> 4;
            int col = (q & 15) * 4;
            *(float4*)&Fs[row][col] =
                *(const float4*)(fb + (size_t)(c0 + row) * NPTS + col);
        }
        __syncthreads();
        #pragma unroll 2
        for (int c = 0; c < KC; ++c) {
            float4 wa  = *(const float4*)&W1s[c][hid0];
            float4 wb  = *(const float4*)&W1s[c][hid0 + 4];
            float4 fa  = *(const float4*)&Fs[c][pt0];
            float4 fb2 = *(const float4*)&Fs[c][pt0 + 4];
            float wv[8] = {wa.x, wa.y, wa.z, wa.w, wb.x, wb.y, wb.z, wb.w};
            float fv[8] = {fa.x, fa.y, fa.z, fa.w, fb2.x, fb2.y, fb2.z, fb2.w};
            #pragma unroll
            for (int j = 0; j < 8; ++j)
                #pragma unroll
                for (int p = 0; p < 8; ++p)
                    acc[j][p] = fmaf(wv[j], fv[p], acc[j][p]);
        }
    }
    __syncthreads();  // LDS free for reuse below

    // bias + relu (in place)
    #pragma unroll
    for (int j = 0; j < 8; ++j) {
        float bias = b1[hid0 + j];
        #pragma unroll
        for (int p = 0; p < 8; ++p) acc[j][p] = fmaxf(acc[j][p] + bias, 0.f);
    }

    // FC2: per-thread partials over its 8 hids, shfl-reduce over the 8 g_h
    // groups (lanes l, l^8, l^16, l^32 share g_p), then cross-wave via LDS.
    float (*red)[TN][NOUT] = (float (*)[TN][NOUT])W1s;  // [4][64][8] = 8 KB

    #pragma unroll
    for (int o = 0; o < NOUT; ++o) {
        float w2v[8];
        #pragma unroll
        for (int j = 0; j < 8; ++j) w2v[j] = W2[(hid0 + j) * NOUT + o];
        float s[8];
        #pragma unroll
        for (int p = 0; p < 8; ++p) {
            float t = 0.f;
            #pragma unroll
            for (int j = 0; j < 8; ++j) t = fmaf(acc[j][p], w2v[j], t);
            s[p] = t;
        }
        #pragma unroll
        for (int m = 8; m <= 32; m <<= 1)
            #pragma unroll
            for (int p = 0; p < 8; ++p) s[p] += __shfl_xor(s[p], m);
        if (g_h == 0) {
            #pragma unroll
            for (int p = 0; p < 8; ++p) red[w][g_p * 8 + p][o] = s[p];
        }
    }
    __syncthreads();

    // combine 4 wave partials, add b2, write prop (+score for o==7)
    #pragma unroll
    for (int r2 = 0; r2 < 2; ++r2) {
        int r        = tid * 2 + r2;
        int pt_local = r >> 3;
        int o        = r & 7;
        float v = red[0][pt_local][o] + red[1][pt_local][o] +
                  red[2][pt_local][o] + red[3][pt_local][o] + b2[o];
        int pt = ptbase + pt_local;
        prop[((size_t)b * NPTS + pt) * NOUT + o] = v;
        if (o == 7) score[(size_t)b * NPTS + pt] = v;
    }
}

// ---------------------------------------------------------------------------
// Kernel 2: per-batch exact top-512 (radix-select on sortable keys) + bitonic
// sort (key desc, idx asc == lax.top_k stable order) + gather. grid=8, block=1024.
// ---------------------------------------------------------------------------
__global__ __launch_bounds__(1024)
void topk_kernel(const float* __restrict__ score,
                 const float* __restrict__ prop,
                 float* __restrict__ out)
{
    const int b   = blockIdx.x;
    const int tid = threadIdx.x;
    constexpr int NT = 1024;

    __shared__ unsigned hist[256];
    __shared__ unsigned sh_prefix;
    __shared__ int      sh_krem;
    __shared__ unsigned ck[KTOP];
    __shared__ int      ci[KTOP];
    __shared__ int      tie_idx[1024];
    __shared__ int      cnt_g, cnt_e;

    const float* sc = score + (size_t)b * NPTS;

    // ---- 4-pass radix select: exact key of the K-th largest --------------
    unsigned prefix = 0;
    int krem = KTOP;
    for (int pass = 0; pass < 4; ++pass) {
        const int shift = 24 - 8 * pass;
        if (tid < 256) hist[tid] = 0;
        __syncthreads();
        for (int i = tid; i < NPTS; i += NT) {
            unsigned u = __float_as_uint(sc[i]);
            unsigned k = (u & 0x80000000u) ? ~u : (u | 0x80000000u);
            if (pass == 0 || (k >> (shift + 8)) == prefix)
                atomicAdd(&hist[(k >> shift) & 255u], 1u);
        }
        __syncthreads();
        if (tid == 0) {
            int cum = 0, bsel = 0;
            for (int bb = 255; bb >= 0; --bb) {
                int c = (int)hist[bb];
                if (cum + c >= krem) { bsel = bb; break; }
                cum += c;
            }
            sh_prefix = (prefix << 8) | (unsigned)bsel;
            sh_krem   = krem - cum;
        }
        __syncthreads();
        prefix = sh_prefix;
        krem   = sh_krem;
        __syncthreads();
    }
    const unsigned thr = prefix;   // exact K-th largest key; krem ties to take

    // ---- select: strictly greater + tie indices --------------------------
    if (tid == 0) { cnt_g = 0; cnt_e = 0; }
    __syncthreads();
    for (int i = tid; i < NPTS; i += NT) {
        unsigned u = __float_as_uint(sc[i]);
        unsigned k = (u & 0x80000000u) ? ~u : (u | 0x80000000u);
        if (k > thr) {
            int p = atomicAdd(&cnt_g, 1);
            if (p < KTOP) { ck[p] = k; ci[p] = i; }
        } else if (k == thr) {
            int p = atomicAdd(&cnt_e, 1);
            if (p < 1024) tie_idx[p] = i;
        }
    }
    __syncthreads();
    const int G  = min(cnt_g, KTOP);
    const int ne = min(cnt_e, 1024);

    // ---- ties: smallest indices first (bitonic asc over 1024) ------------
    for (int i = tid; i < 1024; i += NT)
        if (i >= ne) tie_idx[i] = 0x7FFFFFFF;
    __syncthreads();
    for (int k2 = 2; k2 <= 1024; k2 <<= 1) {
        for (int j = k2 >> 1; j > 0; j >>= 1) {
            int i = tid, ixj = tid ^ j;
            if (ixj > i) {
                int a = tie_idx[i], c = tie_idx[ixj];
                bool up = ((i & k2) == 0);
                if ((a > c) == up) { tie_idx[i] = c; tie_idx[ixj] = a; }
            }
            __syncthreads();
        }
    }
    for (int t = tid; t < krem; t += NT) { ck[G + t] = thr; ci[G + t] = tie_idx[t]; }
    __syncthreads();

    // ---- bitonic sort of exactly 512 entries: key desc, idx asc ----------
    for (int k2 = 2; k2 <= KTOP; k2 <<= 1) {
        for (int j = k2 >> 1; j > 0; j >>= 1) {
            if (tid < KTOP) {
                int i = tid, ixj = tid ^ j;
                if (ixj > i) {
                    unsigned ka = ck[i], kb = ck[ixj];
                    int ia = ci[i], ib = ci[ixj];
                    bool aFirst = (ka > kb) || (ka == kb && ia < ib);
                    bool up = ((i & k2) == 0);
                    if (aFirst != up) {
                        ck[i] = kb; ck[ixj] = ka;
                        ci[i] = ib; ci[ixj] = ia;
                    }
                }
            }
            __syncthreads();
        }
    }

    // ---- gather selected rows --------------------------------------------
    for (int r = tid; r < KTOP * NOUT; r += NT) {
        int row = r >> 3, o = r & 7;
        out[((size_t)b * KTOP + row) * NOUT + o] =
            prop[((size_t)b * NPTS + ci[row]) * NOUT + o];
    }
}

// ---------------------------------------------------------------------------
extern "C" void kernel_launch(void* const* d_in, const int* in_sizes, int n_in,
                              void* d_out, int out_size, void* d_ws, size_t ws_size,
                              hipStream_t stream)
{
    // inputs: 0=points(unused) 1=features 2=W1 3=b1 4=W2 5=b2 6=topk(fixed 512)
    const float* feat = (const float*)d_in[1];
    const float* W1   = (const float*)d_in[2];
    const float* b1   = (const float*)d_in[3];
    const float* W2   = (const float*)d_in[4];
    const float* b2   = (const float*)d_in[5];
    float* out = (float*)d_out;

    float* prop  = (float*)d_ws;                        // [8][65536][8] = 16 MB
    float* score = prop + (size_t)NB * NPTS * NOUT;     // [8][65536]   =  2 MB

    dim3 g1(NPTS / TN, NB);
    hipLaunchKernelGGL(fused_mlp_kernel, g1, dim3(256), 0, stream,
                       feat, W1, b1, W2, b2, prop, score);
    hipLaunchKernelGGL(topk_kernel, dim3(NB), dim3(1024), 0, stream,
                       score, prop, out);
}